// Round 3
// baseline (1624.432 us; speedup 1.0000x reference)
//
#include <hip/hip_runtime.h>
#include <math.h>

// Problem constants
#define BB 64
#define SS 512
#define DD 768
#define HP 96   // padded concat feature dim: 30+30+30 + 6 zero pad
#define RSQRT_P 0.18257418583505537f  // 1/sqrt(30)

__device__ __forceinline__ float dot4(float4 a, float4 b) {
    return a.x*b.x + a.y*b.y + a.z*b.z + a.w*b.w;
}

// ---------------------------------------------------------------------------
// prep: pad/align weights to [Kpad][32] so projection kernels can do uniform
// (scalar) loads with no OOB and no guards.  Wtp[768][32], Wap[96][32],
// Wvp[64][32]; rows >= K and cols >= 30 are zero.
// ---------------------------------------------------------------------------
__global__ __launch_bounds__(256) void prep_kernel(
    const float* __restrict__ Wt, const float* __restrict__ Wa,
    const float* __restrict__ Wv,
    float* __restrict__ Wtp, float* __restrict__ Wap, float* __restrict__ Wvp)
{
    int idx = blockIdx.x * 256 + threadIdx.x;
    if (idx < 768*32) {
        int k = idx >> 5, c = idx & 31;
        Wtp[idx] = (c < 30) ? Wt[k*30 + c] : 0.f;
    } else if (idx < 768*32 + 96*32) {
        int j = idx - 768*32; int k = j >> 5, c = j & 31;
        Wap[j] = (c < 30 && k < 74) ? Wa[k*30 + c] : 0.f;
    } else if (idx < 768*32 + 96*32 + 64*32) {
        int j = idx - (768*32 + 96*32); int k = j >> 5, c = j & 31;
        Wvp[j] = (c < 30 && k < 47) ? Wv[k*30 + c] : 0.f;
    }
}

// ---------------------------------------------------------------------------
// proj: H[row][coff..coff+29] = X[row]@Wp + bias.  One thread = one row x all
// 30 cols (acc in VGPRs, W via uniform scalar loads, X row via LDS b128).
// Block 256 = 256 rows; grid 128.  K chunked by 32 with reg-staged pipeline.
// Text (PADZ) also zeroes H cols 90..95.
// ---------------------------------------------------------------------------
template<int K, int NCH, bool VEC4, bool PADZ>
__global__ __launch_bounds__(256, 4) void proj_kernel(
    const float* __restrict__ X, const float* __restrict__ Wp,
    const float* __restrict__ bias, float* __restrict__ H, int coff)
{
    __shared__ float xs[256*36];   // 36-float stride (32 data + 4 pad)
    const int tid = threadIdx.x;
    const int row0 = blockIdx.x * 256;

    float acc[30];
    #pragma unroll
    for (int c = 0; c < 30; ++c) acc[c] = 0.f;

    float4 rb4[8];
    float  rbs[32];

    // ---- load chunk `ch` of X into registers (issue only; no LDS) ----
    auto LOAD = [&](int ch) {
        const int kb = ch * 32;
        if (VEC4) {
            #pragma unroll
            for (int i = 0; i < 8; ++i) {
                int idx = tid + i*256;
                int r = idx >> 3, c4 = idx & 7;
                rb4[i] = *(const float4*)&X[(size_t)(row0 + r)*K + kb + c4*4];
            }
        } else {
            #pragma unroll
            for (int i = 0; i < 32; ++i) {
                int idx = tid + i*256;
                int r = idx >> 5, c = idx & 31;
                rbs[i] = (kb + c < K) ? X[(size_t)(row0 + r)*K + kb + c] : 0.f;
            }
        }
    };
    auto STORE = [&]() {
        if (VEC4) {
            #pragma unroll
            for (int i = 0; i < 8; ++i) {
                int idx = tid + i*256;
                int r = idx >> 3, c4 = idx & 7;
                *(float4*)&xs[r*36 + c4*4] = rb4[i];
            }
        } else {
            #pragma unroll
            for (int i = 0; i < 32; ++i) {
                int idx = tid + i*256;
                int r = idx >> 5, c = idx & 31;
                xs[r*36 + c] = rbs[i];
            }
        }
    };

    LOAD(0);
    for (int ch = 0; ch < NCH; ++ch) {
        __syncthreads();          // previous compute done reading xs
        STORE();
        __syncthreads();
        if (ch + 1 < NCH) LOAD(ch + 1);   // issue next-chunk globals early
        const int kb = ch * 32;
        const float* __restrict__ xrow = xs + tid*36;
        #pragma unroll
        for (int k4 = 0; k4 < 8; ++k4) {
            float4 x = *(const float4*)&xrow[k4*4];
            const float* __restrict__ wr = Wp + (size_t)(kb + k4*4)*32;
            #pragma unroll
            for (int j = 0; j < 4; ++j) {
                float xj = (j==0) ? x.x : (j==1) ? x.y : (j==2) ? x.z : x.w;
                #pragma unroll
                for (int c = 0; c < 30; ++c)
                    acc[c] = fmaf(xj, wr[j*32 + c], acc[c]);
            }
        }
    }

    // ---- transpose through LDS (stride 33: conflict-free), coalesced store
    __syncthreads();
    #pragma unroll
    for (int c = 0; c < 30; ++c) xs[tid*33 + c] = acc[c];
    __syncthreads();
    const int STW = PADZ ? 36 : 30;
    #pragma unroll
    for (int i = 0; i < (PADZ ? 36 : 30); ++i) {
        int idx = tid + i*256;
        int r = idx / STW, c = idx - r*STW;
        float v; int cc;
        if (c < 30) { v = xs[r*33 + c] + bias[c]; cc = coff + c; }
        else        { v = 0.f;                    cc = 90 + (c - 30); }
        H[(size_t)(row0 + r)*HP + cc] = v;
    }
}

// ---------------------------------------------------------------------------
// sim: out2 = relu((H_b @ H_b^T)/sqrt(30)).  128x128 tile, 8x8 per thread,
// K=96 in 2 chunks of 48.  Per-lane k-rotation spreads LDS banks.
// ---------------------------------------------------------------------------
__global__ __launch_bounds__(256, 3) void sim_kernel(
    const float* __restrict__ H, float* __restrict__ out2)
{
    __shared__ float as[128*52];
    __shared__ float bs[128*52];
    const int tid = threadIdx.x;
    const int b  = blockIdx.z;
    const int i0 = blockIdx.y * 128, j0 = blockIdx.x * 128;
    const float* __restrict__ Hb = H + (size_t)b * SS * HP;
    const int tx = tid & 15, ty = tid >> 4;

    float acc[8][8] = {};
    for (int ch = 0; ch < 2; ++ch) {
        __syncthreads();
        #pragma unroll
        for (int i = 0; i < 6; ++i) {           // 1536 float4 per matrix
            int idx = tid + i*256;
            int r = idx / 12, c4 = idx % 12;
            *(float4*)&as[r*52 + c4*4] = *(const float4*)&Hb[(size_t)(i0 + r)*HP + ch*48 + c4*4];
            *(float4*)&bs[r*52 + c4*4] = *(const float4*)&Hb[(size_t)(j0 + r)*HP + ch*48 + c4*4];
        }
        __syncthreads();
        int kk = tx; if (kk >= 12) kk -= 12;    // per-lane k rotation
        #pragma unroll
        for (int k4 = 0; k4 < 12; ++k4) {
            float4 av[8], bv[8];
            #pragma unroll
            for (int ii = 0; ii < 8; ++ii) av[ii] = *(const float4*)&as[(ty*8 + ii)*52 + kk*4];
            #pragma unroll
            for (int jj = 0; jj < 8; ++jj) bv[jj] = *(const float4*)&bs[(tx*8 + jj)*52 + kk*4];
            #pragma unroll
            for (int ii = 0; ii < 8; ++ii)
                #pragma unroll
                for (int jj = 0; jj < 8; ++jj)
                    acc[ii][jj] += dot4(av[ii], bv[jj]);
            ++kk; if (kk == 12) kk = 0;
        }
    }

    float* __restrict__ o = out2 + (size_t)b * SS * SS;
    #pragma unroll
    for (int ii = 0; ii < 8; ++ii) {
        int i = i0 + ty*8 + ii;
        #pragma unroll
        for (int jq = 0; jq < 2; ++jq) {
            float4 v;
            v.x = fmaxf(acc[ii][jq*4+0] * RSQRT_P, 0.f);
            v.y = fmaxf(acc[ii][jq*4+1] * RSQRT_P, 0.f);
            v.z = fmaxf(acc[ii][jq*4+2] * RSQRT_P, 0.f);
            v.w = fmaxf(acc[ii][jq*4+3] * RSQRT_P, 0.f);
            *(float4*)&o[(size_t)i*SS + j0 + tx*8 + jq*4] = v;
        }
    }
}

// ---------------------------------------------------------------------------
// pv: row-0 logits + softmax + PV.  Grid (64,6): batch x 128-wide d slice.
// 2-way t-split uses all 256 threads in the PV loop.
// ---------------------------------------------------------------------------
__global__ __launch_bounds__(256) void pv_kernel(
    const float* __restrict__ H, const float* __restrict__ hidden,
    const float* __restrict__ amask, float* __restrict__ fd)
{
    __shared__ float sf[512];
    __shared__ float red[256];
    __shared__ float h0[96];
    const int tid = threadIdx.x;
    const int b = blockIdx.x, slice = blockIdx.y;
    const float* __restrict__ Hb = H + (size_t)b * SS * HP;

    if (tid < 24) *(float4*)&h0[tid*4] = *(const float4*)&Hb[tid*4];
    __syncthreads();

    for (int t = tid; t < 512; t += 256) {
        const float* __restrict__ hr = Hb + (size_t)t*HP;
        float s = 0.f;
        #pragma unroll
        for (int k = 0; k < 96; k += 4) {
            float4 x = *(const float4*)&hr[k];
            s += x.x*h0[k] + x.y*h0[k+1] + x.z*h0[k+2] + x.w*h0[k+3];
        }
        sf[t] = s * RSQRT_P + amask[b*SS + t];   // row-constant mask term cancels
    }
    __syncthreads();
    red[tid] = fmaxf(sf[tid], sf[tid + 256]);
    __syncthreads();
    for (int s2 = 128; s2 > 0; s2 >>= 1) {
        if (tid < s2) red[tid] = fmaxf(red[tid], red[tid + s2]);
        __syncthreads();
    }
    const float M = red[0];
    __syncthreads();
    float e0 = __expf(sf[tid] - M), e1 = __expf(sf[tid + 256] - M);
    sf[tid] = e0; sf[tid + 256] = e1;
    red[tid] = e0 + e1;
    __syncthreads();
    for (int s2 = 128; s2 > 0; s2 >>= 1) {
        if (tid < s2) red[tid] += red[tid + s2];
        __syncthreads();
    }
    const float inv = 1.f / red[0];
    __syncthreads();

    const int dl = tid & 127, th = tid >> 7;
    const int d = slice*128 + dl;
    const float* __restrict__ hp = hidden + ((size_t)b*SS + th*256)*DD + d;
    const float* __restrict__ sfh = sf + th*256;
    float a0 = 0.f, a1 = 0.f, a2 = 0.f, a3 = 0.f;
    for (int t = 0; t < 256; t += 4) {
        a0 += sfh[t]   * hp[(size_t)t*DD];
        a1 += sfh[t+1] * hp[(size_t)(t+1)*DD];
        a2 += sfh[t+2] * hp[(size_t)(t+2)*DD];
        a3 += sfh[t+3] * hp[(size_t)(t+3)*DD];
    }
    red[tid] = a0 + a1 + a2 + a3;
    __syncthreads();
    if (th == 0)
        fd[b*DD + d] = (red[dl] + red[128 + dl]) * inv + hidden[(size_t)b*SS*DD + d];
}

// ---------------------------------------------------------------------------
// dense: h = fd[64,768] @ Wd[768,768] + bd.  Grid (12,4).
// ---------------------------------------------------------------------------
__global__ __launch_bounds__(256) void dense_kernel(
    const float* __restrict__ fd, const float* __restrict__ Wd,
    const float* __restrict__ bd, float* __restrict__ hout)
{
    __shared__ float fds[16*68];
    __shared__ float wds[64*68];
    const int tid = threadIdx.x;
    const int bn0 = blockIdx.x * 64, bm0 = blockIdx.y * 16;
    const int tx = tid & 63, ty = tid >> 6;
    float acc[4] = {};
    for (int kc = 0; kc < 12; ++kc) {
        __syncthreads();
        {
            int r = tid >> 4, c4 = tid & 15;
            *(float4*)&fds[r*68 + c4*4] = *(const float4*)&fd[(size_t)(bm0 + r)*768 + kc*64 + c4*4];
        }
        #pragma unroll
        for (int i = 0; i < 4; ++i) {
            int idx = tid + i*256;
            int k = idx >> 4, c4 = idx & 15;
            *(float4*)&wds[k*68 + c4*4] = *(const float4*)&Wd[(size_t)(kc*64 + k)*768 + bn0 + c4*4];
        }
        __syncthreads();
        #pragma unroll 16
        for (int k = 0; k < 64; ++k) {
            float w = wds[k*68 + tx];
            #pragma unroll
            for (int rr = 0; rr < 4; ++rr)
                acc[rr] += fds[(ty + 4*rr)*68 + k] * w;
        }
    }
    float bias = bd[bn0 + tx];
    #pragma unroll
    for (int rr = 0; rr < 4; ++rr)
        hout[(size_t)(bm0 + ty + 4*rr)*768 + bn0 + tx] = acc[rr] + bias;
}

// ---------------------------------------------------------------------------
// ln: LayerNorm over 64 rows of 768 -> out1.
// ---------------------------------------------------------------------------
__global__ __launch_bounds__(256) void ln_kernel(
    const float* __restrict__ hin, const float* __restrict__ g,
    const float* __restrict__ bta, float* __restrict__ out1)
{
    __shared__ float red[256];
    const int tid = threadIdx.x;
    const int row = blockIdx.x;
    const float* __restrict__ hr = hin + (size_t)row*768;
    float v0 = hr[tid], v1 = hr[tid + 256], v2 = hr[tid + 512];
    red[tid] = v0 + v1 + v2;
    __syncthreads();
    for (int s2 = 128; s2 > 0; s2 >>= 1) {
        if (tid < s2) red[tid] += red[tid + s2];
        __syncthreads();
    }
    const float mu = red[0] * (1.f/768.f);
    __syncthreads();
    float d0 = v0 - mu, d1 = v1 - mu, d2 = v2 - mu;
    red[tid] = d0*d0 + d1*d1 + d2*d2;
    __syncthreads();
    for (int s2 = 128; s2 > 0; s2 >>= 1) {
        if (tid < s2) red[tid] += red[tid + s2];
        __syncthreads();
    }
    const float var = red[0] * (1.f/768.f);
    const float inv = 1.f / sqrtf(var + 1e-12f);
    out1[(size_t)row*768 + tid]       = d0*inv*g[tid]       + bta[tid];
    out1[(size_t)row*768 + tid + 256] = d1*inv*g[tid + 256] + bta[tid + 256];
    out1[(size_t)row*768 + tid + 512] = d2*inv*g[tid + 512] + bta[tid + 512];
}

// ---------------------------------------------------------------------------
extern "C" void kernel_launch(void* const* d_in, const int* in_sizes, int n_in,
                              void* d_out, int out_size, void* d_ws, size_t ws_size,
                              hipStream_t stream) {
    (void)in_sizes; (void)n_in; (void)out_size; (void)ws_size;
    const float* hidden = (const float*)d_in[0];
    // d_in[1] pooled_output: unused by reference
    const float* audio  = (const float*)d_in[2];
    const float* video  = (const float*)d_in[3];
    const float* amask  = (const float*)d_in[4];
    const float* Wt = (const float*)d_in[5];
    const float* bt = (const float*)d_in[6];
    const float* Wa = (const float*)d_in[7];
    const float* ba = (const float*)d_in[8];
    const float* Wv = (const float*)d_in[9];
    const float* bv = (const float*)d_in[10];
    const float* Wd = (const float*)d_in[11];
    const float* bd = (const float*)d_in[12];
    const float* lng = (const float*)d_in[13];
    const float* lnb = (const float*)d_in[14];

    float* out1 = (float*)d_out;                      // [64,768]
    float* out2 = (float*)d_out + (size_t)BB*DD;      // [64,512,512]

    float* H    = (float*)d_ws;                       // 64*512*96
    float* Wtp  = H   + (size_t)BB*SS*HP;             // 768*32
    float* Wap  = Wtp + 768*32;                       // 96*32
    float* Wvp  = Wap + 96*32;                        // 64*32
    float* fd   = Wvp + 64*32;                        // 64*768
    float* hmid = fd  + (size_t)BB*DD;                // 64*768

    prep_kernel<<<116, 256, 0, stream>>>(Wt, Wa, Wv, Wtp, Wap, Wvp);
    proj_kernel<768, 24, true,  true ><<<128, 256, 0, stream>>>(hidden, Wtp, bt, H, 0);
    proj_kernel< 74,  3, false, false><<<128, 256, 0, stream>>>(audio,  Wap, ba, H, 30);
    proj_kernel< 47,  2, false, false><<<128, 256, 0, stream>>>(video,  Wvp, bv, H, 60);
    sim_kernel<<<dim3(4, 4, 64), 256, 0, stream>>>(H, out2);
    pv_kernel<<<dim3(64, 6), 256, 0, stream>>>(H, hidden, amask, fd);
    dense_kernel<<<dim3(12, 4), 256, 0, stream>>>(fd, Wd, bd, hmid);
    ln_kernel<<<64, 256, 0, stream>>>(hmid, lng, lnb, out1);
}

// Round 7
// 474.371 us; speedup vs baseline: 3.4244x; 3.4244x over previous
//
#include <hip/hip_runtime.h>
#include <math.h>

// Problem constants
#define BB 64
#define SS 512
#define DD 768
#define HP 96   // bf16 H row length: 30+30+30 + 6 zero pad
#define RSQRT_P 0.18257418583505537f  // 1/sqrt(30)

using bf8 = __attribute__((ext_vector_type(8))) short;   // 8 bf16 (4 VGPR)
using f32x4 = __attribute__((ext_vector_type(4))) float; // MFMA acc frag

__device__ __forceinline__ float b2f(short s) {
    return __uint_as_float(((unsigned)(unsigned short)s) << 16);
}
__device__ __forceinline__ short f2b(float x) {          // RNE f32->bf16
    unsigned u = __float_as_uint(x);
    return (short)((u + 0x7FFFu + ((u >> 16) & 1u)) >> 16);
}
__device__ __forceinline__ float lo16f(int u) { return __uint_as_float(((unsigned)u) << 16); }
__device__ __forceinline__ float hi16f(int u) { return __uint_as_float(((unsigned)u) & 0xFFFF0000u); }

// ---------------------------------------------------------------------------
// prep: pad weights to [Kpad][32] f32 so proj kernels use uniform s_loads.
// ---------------------------------------------------------------------------
__global__ __launch_bounds__(256) void prep_kernel(
    const float* __restrict__ Wt, const float* __restrict__ Wa,
    const float* __restrict__ Wv,
    float* __restrict__ Wtp, float* __restrict__ Wap, float* __restrict__ Wvp)
{
    int idx = blockIdx.x * 256 + threadIdx.x;
    if (idx < 768*32) {
        int k = idx >> 5, c = idx & 31;
        Wtp[idx] = (c < 30) ? Wt[k*30 + c] : 0.f;
    } else if (idx < 768*32 + 96*32) {
        int j = idx - 768*32; int k = j >> 5, c = j & 31;
        Wap[j] = (c < 30 && k < 74) ? Wa[k*30 + c] : 0.f;
    } else if (idx < 768*32 + 96*32 + 64*32) {
        int j = idx - (768*32 + 96*32); int k = j >> 5, c = j & 31;
        Wvp[j] = (c < 30 && k < 47) ? Wv[k*30 + c] : 0.f;
    }
}

// ---------------------------------------------------------------------------
// proj_t: text projection, K=768.  512 blocks x 64 rows; thread = (row, K-
// quarter): 4 partial acc[30] per row, LDS-reduced.  W via wave-uniform
// s_loads (quarter == wave).  Emits Hhi/Hlo bf16 (+ zero pad cols 90..95).
// ---------------------------------------------------------------------------
__global__ __launch_bounds__(256) void proj_t_kernel(
    const float* __restrict__ X, const float* __restrict__ Wp,
    const float* __restrict__ bias, short* __restrict__ Hhi,
    short* __restrict__ Hlo)
{
    __shared__ float xs[8448];          // [64][132] band  /  [256][33] reduce
    const int tid = threadIdx.x;
    const int row0 = blockIdx.x * 64;
    const int rl = tid & 63, q = tid >> 6;   // row-local, K-quarter (==wave)

    float acc[30];
    #pragma unroll
    for (int c = 0; c < 30; ++c) acc[c] = 0.f;

    for (int m = 0; m < 6; ++m) {       // 6 macro-chunks of 128 k
        __syncthreads();
        #pragma unroll
        for (int i = 0; i < 8; ++i) {   // stage X[64][128] f32
            int idx = tid + i*256;
            int r = idx >> 5, c4 = idx & 31;
            *(float4*)&xs[r*132 + c4*4] =
                *(const float4*)&X[(size_t)(row0 + r)*768 + m*128 + c4*4];
        }
        __syncthreads();
        const int kc = m*4 + q;         // this quarter's 32-k chunk
        #pragma unroll
        for (int k4 = 0; k4 < 8; ++k4) {
            float4 x = *(const float4*)&xs[rl*132 + q*32 + k4*4];
            const float* __restrict__ wr = Wp + (size_t)(kc*32 + k4*4)*32;
            #pragma unroll
            for (int j = 0; j < 4; ++j) {
                float xj = (j==0) ? x.x : (j==1) ? x.y : (j==2) ? x.z : x.w;
                #pragma unroll
                for (int c = 0; c < 30; ++c)
                    acc[c] = fmaf(xj, wr[j*32 + c], acc[c]);
            }
        }
    }

    // reduce 4 quarters, split to hi/lo bf16
    __syncthreads();
    #pragma unroll
    for (int c = 0; c < 30; ++c) xs[tid*33 + c] = acc[c];
    __syncthreads();
    #pragma unroll
    for (int i = 0; i < 8; ++i) {       // 1920 outputs
        int idx = tid + i*256;
        if (idx < 1920) {
            int r = idx / 30, c = idx - r*30;
            float v = xs[r*33 + c] + xs[(64 + r)*33 + c]
                    + xs[(128 + r)*33 + c] + xs[(192 + r)*33 + c] + bias[c];
            short hi = f2b(v);
            short lo = f2b(v - b2f(hi));
            Hhi[(size_t)(row0 + r)*HP + c] = hi;
            Hlo[(size_t)(row0 + r)*HP + c] = lo;
        }
    }
    for (int idx = tid; idx < 384; idx += 256) {   // zero pad cols 90..95
        int r = idx / 6, c = 90 + idx % 6;
        Hhi[(size_t)(row0 + r)*HP + c] = 0;
        Hlo[(size_t)(row0 + r)*HP + c] = 0;
    }
}

// ---------------------------------------------------------------------------
// proj_s: small-K projections (audio 74, video 47).  Thread = row x 30 cols,
// W via uniform s_loads.  Emits Hhi/Hlo at column offset coff.
// ---------------------------------------------------------------------------
template<int K, int NCH>
__global__ __launch_bounds__(256, 4) void proj_s_kernel(
    const float* __restrict__ X, const float* __restrict__ Wp,
    const float* __restrict__ bias, short* __restrict__ Hhi,
    short* __restrict__ Hlo, int coff)
{
    __shared__ float xs[256*36];
    const int tid = threadIdx.x;
    const int row0 = blockIdx.x * 256;

    float acc[30];
    #pragma unroll
    for (int c = 0; c < 30; ++c) acc[c] = 0.f;

    for (int ch = 0; ch < NCH; ++ch) {
        const int kb = ch * 32;
        __syncthreads();
        #pragma unroll
        for (int i = 0; i < 32; ++i) {
            int idx = tid + i*256;
            int r = idx >> 5, c = idx & 31;
            xs[r*36 + c] = (kb + c < K) ? X[(size_t)(row0 + r)*K + kb + c] : 0.f;
        }
        __syncthreads();
        const float* __restrict__ xrow = xs + tid*36;
        #pragma unroll
        for (int k4 = 0; k4 < 8; ++k4) {
            float4 x = *(const float4*)&xrow[k4*4];
            const float* __restrict__ wr = Wp + (size_t)(kb + k4*4)*32;
            #pragma unroll
            for (int j = 0; j < 4; ++j) {
                float xj = (j==0) ? x.x : (j==1) ? x.y : (j==2) ? x.z : x.w;
                #pragma unroll
                for (int c = 0; c < 30; ++c)
                    acc[c] = fmaf(xj, wr[j*32 + c], acc[c]);
            }
        }
    }

    __syncthreads();
    #pragma unroll
    for (int c = 0; c < 30; ++c) xs[tid*33 + c] = acc[c];
    __syncthreads();
    #pragma unroll
    for (int i = 0; i < 30; ++i) {
        int idx = tid + i*256;
        int r = idx / 30, c = idx - r*30;
        float v = xs[r*33 + c] + bias[c];
        short hi = f2b(v);
        short lo = f2b(v - b2f(hi));
        Hhi[(size_t)(row0 + r)*HP + coff + c] = hi;
        Hlo[(size_t)(row0 + r)*HP + coff + c] = lo;
    }
}

// ---------------------------------------------------------------------------
// sim: out2 = relu((H H^T)/sqrt(30)) via bf16 MFMA, hi/lo 3-term split
// (hi.hi + hi.lo + lo.hi ~ fp32).  128x128 tile/block, 4 waves, 64x64/wave.
// 3 LDS buffers (80 KB -> 2 blocks/CU).  XCD-swizzled grid (1024 % 8 == 0).
// ---------------------------------------------------------------------------
__global__ __launch_bounds__(256) void sim_kernel(
    const short* __restrict__ Hhi, const short* __restrict__ Hlo,
    float* __restrict__ out2)
{
    __shared__ __align__(16) short as_[128*104];   // Ahi
    __shared__ __align__(16) short bs_[128*104];   // Bhi
    __shared__ __align__(16) short cs_[128*104];   // Blo, then Alo
    const int tid = threadIdx.x;

    int wg = ((blockIdx.x & 7) << 7) | (blockIdx.x >> 3);  // XCD swizzle
    const int b  = wg >> 4;
    const int rem = wg & 15;
    const int i0 = (rem >> 2) * 128, j0 = (rem & 3) * 128;

    const int lane = tid & 63, wave = tid >> 6;
    const int lr = lane & 15, kg = lane >> 4;
    const int wr = (wave >> 1) * 64, wc = (wave & 1) * 64;

    auto stage = [&](short* dst, const short* src) {
        #pragma unroll
        for (int i = 0; i < 6; ++i) {
            int idx = tid + i*256;
            int r = idx / 12, c = idx % 12;
            *(float4*)&dst[r*104 + c*8] = *(const float4*)&src[(size_t)r*HP + c*8];
        }
    };

    f32x4 acc[4][4] = {};

    auto mmacc = [&](const short* A, const short* Bp) {
        #pragma unroll
        for (int kc = 0; kc < 3; ++kc) {
            const int ko = kc*32 + kg*8;
            bf8 a[4], bv[4];
            #pragma unroll
            for (int f = 0; f < 4; ++f)
                a[f] = *(const bf8*)&A[(wr + f*16 + lr)*104 + ko];
            #pragma unroll
            for (int f = 0; f < 4; ++f)
                bv[f] = *(const bf8*)&Bp[(wc + f*16 + lr)*104 + ko];
            #pragma unroll
            for (int fi = 0; fi < 4; ++fi)
                #pragma unroll
                for (int fj = 0; fj < 4; ++fj)
                    acc[fi][fj] = __builtin_amdgcn_mfma_f32_16x16x32_bf16(
                        a[fi], bv[fj], acc[fi][fj], 0, 0, 0);
        }
    };

    const short* HhiA = Hhi + ((size_t)b*SS + i0)*HP;
    const short* HhiB = Hhi + ((size_t)b*SS + j0)*HP;
    const short* HloA = Hlo + ((size_t)b*SS + i0)*HP;
    const short* HloB = Hlo + ((size_t)b*SS + j0)*HP;

    stage(as_, HhiA); stage(bs_, HhiB); stage(cs_, HloB);
    __syncthreads();
    mmacc(as_, bs_);          // hi . hi
    mmacc(as_, cs_);          // hi . lo
    __syncthreads();          // all waves done reading cs_
    stage(cs_, HloA);
    __syncthreads();
    mmacc(cs_, bs_);          // lo . hi

    float* __restrict__ o = out2 + (size_t)b * SS * SS;
    const int ibase = i0 + wr, jbase = j0 + wc;
    #pragma unroll
    for (int fi = 0; fi < 4; ++fi) {
        #pragma unroll
        for (int r4 = 0; r4 < 4; ++r4) {
            const int gi = ibase + fi*16 + kg*4 + r4;
            #pragma unroll
            for (int fj = 0; fj < 4; ++fj) {
                float v = acc[fi][fj][r4] * RSQRT_P;
                o[(size_t)gi*SS + jbase + fj*16 + lr] = fmaxf(v, 0.f);
            }
        }
    }
}

// ---------------------------------------------------------------------------
// pv: row-0 logits (from hi+lo reconstruction) + softmax + PV.
// Grid (64,6): batch x 128-wide d slice.
// ---------------------------------------------------------------------------
__global__ __launch_bounds__(256) void pv_kernel(
    const short* __restrict__ Hhi, const short* __restrict__ Hlo,
    const float* __restrict__ hidden, const float* __restrict__ amask,
    float* __restrict__ fd)
{
    __shared__ float sf[512];
    __shared__ float red[256];
    __shared__ float h0[96];
    const int tid = threadIdx.x;
    const int b = blockIdx.x, slice = blockIdx.y;

    if (tid < 96)
        h0[tid] = b2f(Hhi[(size_t)b*SS*HP + tid]) + b2f(Hlo[(size_t)b*SS*HP + tid]);
    __syncthreads();

    for (int t = tid; t < 512; t += 256) {
        const int4* rh = (const int4*)(Hhi + ((size_t)b*SS + t)*HP);
        const int4* rl = (const int4*)(Hlo + ((size_t)b*SS + t)*HP);
        float s = 0.f;
        #pragma unroll
        for (int k4 = 0; k4 < 12; ++k4) {
            int4 xh = rh[k4]; int4 xl = rl[k4];
            const float* hp = h0 + k4*8;
            s += (lo16f(xh.x) + lo16f(xl.x)) * hp[0];
            s += (hi16f(xh.x) + hi16f(xl.x)) * hp[1];
            s += (lo16f(xh.y) + lo16f(xl.y)) * hp[2];
            s += (hi16f(xh.y) + hi16f(xl.y)) * hp[3];
            s += (lo16f(xh.z) + lo16f(xl.z)) * hp[4];
            s += (hi16f(xh.z) + hi16f(xl.z)) * hp[5];
            s += (lo16f(xh.w) + lo16f(xl.w)) * hp[6];
            s += (hi16f(xh.w) + hi16f(xl.w)) * hp[7];
        }
        sf[t] = s * RSQRT_P + amask[b*SS + t];   // row-constant mask term cancels
    }
    __syncthreads();
    red[tid] = fmaxf(sf[tid], sf[tid + 256]);
    __syncthreads();
    for (int s2 = 128; s2 > 0; s2 >>= 1) {
        if (tid < s2) red[tid] = fmaxf(red[tid], red[tid + s2]);
        __syncthreads();
    }
    const float M = red[0];
    __syncthreads();
    float e0 = __expf(sf[tid] - M), e1 = __expf(sf[tid + 256] - M);
    sf[tid] = e0; sf[tid + 256] = e1;
    red[tid] = e0 + e1;
    __syncthreads();
    for (int s2 = 128; s2 > 0; s2 >>= 1) {
        if (tid < s2) red[tid] += red[tid + s2];
        __syncthreads();
    }
    const float inv = 1.f / red[0];
    __syncthreads();

    const int dl = tid & 127, th = tid >> 7;
    const int d = slice*128 + dl;
    const float* __restrict__ hp = hidden + ((size_t)b*SS + th*256)*DD + d;
    const float* __restrict__ sfh = sf + th*256;
    float a0 = 0.f, a1 = 0.f, a2 = 0.f, a3 = 0.f;
    for (int t = 0; t < 256; t += 4) {
        a0 += sfh[t]   * hp[(size_t)t*DD];
        a1 += sfh[t+1] * hp[(size_t)(t+1)*DD];
        a2 += sfh[t+2] * hp[(size_t)(t+2)*DD];
        a3 += sfh[t+3] * hp[(size_t)(t+3)*DD];
    }
    red[tid] = a0 + a1 + a2 + a3;
    __syncthreads();
    if (th == 0)
        fd[b*DD + d] = (red[dl] + red[128 + dl]) * inv + hidden[(size_t)b*SS*DD + d];
}

// ---------------------------------------------------------------------------
// dense: h = fd[64,768] @ Wd[768,768] + bd.  Grid (12,4).
// ---------------------------------------------------------------------------
__global__ __launch_bounds__(256) void dense_kernel(
    const float* __restrict__ fd, const float* __restrict__ Wd,
    const float* __restrict__ bd, float* __restrict__ hout)
{
    __shared__ float fds[16*68];
    __shared__ float wds[64*68];
    const int tid = threadIdx.x;
    const int bn0 = blockIdx.x * 64, bm0 = blockIdx.y * 16;
    const int tx = tid & 63, ty = tid >> 6;
    float acc[4] = {};
    for (int kc = 0; kc < 12; ++kc) {
        __syncthreads();
        {
            int r = tid >> 4, c4 = tid & 15;
            *(float4*)&fds[r*68 + c4*4] = *(const float4*)&fd[(size_t)(bm0 + r)*768 + kc*64 + c4*4];
        }
        #pragma unroll
        for (int i = 0; i < 4; ++i) {
            int idx = tid + i*256;
            int k = idx >> 4, c4 = idx & 15;
            *(float4*)&wds[k*68 + c4*4] = *(const float4*)&Wd[(size_t)(kc*64 + k)*768 + bn0 + c4*4];
        }
        __syncthreads();
        #pragma unroll 16
        for (int k = 0; k < 64; ++k) {
            float w = wds[k*68 + tx];
            #pragma unroll
            for (int rr = 0; rr < 4; ++rr)
                acc[rr] += fds[(ty + 4*rr)*68 + k] * w;
        }
    }
    float bias = bd[bn0 + tx];
    #pragma unroll
    for (int rr = 0; rr < 4; ++rr)
        hout[(size_t)(bm0 + ty + 4*rr)*768 + bn0 + tx] = acc[rr] + bias;
}

// ---------------------------------------------------------------------------
// ln: LayerNorm over 64 rows of 768 -> out1.
// ---------------------------------------------------------------------------
__global__ __launch_bounds__(256) void ln_kernel(
    const float* __restrict__ hin, const float* __restrict__ g,
    const float* __restrict__ bta, float* __restrict__ out1)
{
    __shared__ float red[256];
    const int tid = threadIdx.x;
    const int row = blockIdx.x;
    const float* __restrict__ hr = hin + (size_t)row*768;
    float v0 = hr[tid], v1 = hr[tid + 256], v2 = hr[tid + 512];
    red[tid] = v0 + v1 + v2;
    __syncthreads();
    for (int s2 = 128; s2 > 0; s2 >>= 1) {
        if (tid < s2) red[tid] += red[tid + s2];
        __syncthreads();
    }
    const float mu = red[0] * (1.f/768.f);
    __syncthreads();
    float d0 = v0 - mu, d1 = v1 - mu, d2 = v2 - mu;
    red[tid] = d0*d0 + d1*d1 + d2*d2;
    __syncthreads();
    for (int s2 = 128; s2 > 0; s2 >>= 1) {
        if (tid < s2) red[tid] += red[tid + s2];
        __syncthreads();
    }
    const float var = red[0] * (1.f/768.f);
    const float inv = 1.f / sqrtf(var + 1e-12f);
    out1[(size_t)row*768 + tid]       = d0*inv*g[tid]       + bta[tid];
    out1[(size_t)row*768 + tid + 256] = d1*inv*g[tid + 256] + bta[tid + 256];
    out1[(size_t)row*768 + tid + 512] = d2*inv*g[tid + 512] + bta[tid + 512];
}

// ---------------------------------------------------------------------------
extern "C" void kernel_launch(void* const* d_in, const int* in_sizes, int n_in,
                              void* d_out, int out_size, void* d_ws, size_t ws_size,
                              hipStream_t stream) {
    (void)in_sizes; (void)n_in; (void)out_size; (void)ws_size;
    const float* hidden = (const float*)d_in[0];
    // d_in[1] pooled_output: unused by reference
    const float* audio  = (const float*)d_in[2];
    const float* video  = (const float*)d_in[3];
    const float* amask  = (const float*)d_in[4];
    const float* Wt = (const float*)d_in[5];
    const float* bt = (const float*)d_in[6];
    const float* Wa = (const float*)d_in[7];
    const float* ba = (const float*)d_in[8];
    const float* Wv = (const float*)d_in[9];
    const float* bv = (const float*)d_in[10];
    const float* Wd = (const float*)d_in[11];
    const float* bd = (const float*)d_in[12];
    const float* lng = (const float*)d_in[13];
    const float* lnb = (const float*)d_in[14];

    float* out1 = (float*)d_out;                      // [64,768]
    float* out2 = (float*)d_out + (size_t)BB*DD;      // [64,512,512]

    float* Wtp  = (float*)d_ws;                       // 768*32
    float* Wap  = Wtp + 768*32;                       // 96*32
    float* Wvp  = Wap + 96*32;                        // 64*32
    float* fd   = Wvp + 64*32;                        // 64*768
    float* hmid = fd  + (size_t)BB*DD;                // 64*768
    short* Hhi  = (short*)(hmid + (size_t)BB*DD);     // 64*512*96 bf16
    short* Hlo  = Hhi + (size_t)BB*SS*HP;             // 64*512*96 bf16

    prep_kernel<<<116, 256, 0, stream>>>(Wt, Wa, Wv, Wtp, Wap, Wvp);
    proj_t_kernel<<<512, 256, 0, stream>>>(hidden, Wtp, bt, Hhi, Hlo);
    proj_s_kernel<74, 3><<<128, 256, 0, stream>>>(audio, Wap, ba, Hhi, Hlo, 30);
    proj_s_kernel<47, 2><<<128, 256, 0, stream>>>(video, Wvp, bv, Hhi, Hlo, 60);
    sim_kernel<<<1024, 256, 0, stream>>>(Hhi, Hlo, out2);
    pv_kernel<<<dim3(64, 6), 256, 0, stream>>>(Hhi, Hlo, hidden, amask, fd);
    dense_kernel<<<dim3(12, 4), 256, 0, stream>>>(fd, Wd, bd, hmid);
    ln_kernel<<<64, 256, 0, stream>>>(hmid, lng, lnb, out1);
}